// Round 4
// baseline (132.967 us; speedup 1.0000x reference)
//
#include <hip/hip_runtime.h>
#include <math.h>

#define NXv 128
#define NYv 128
#define NZv 128
#define NVOX (NXv * NYv * NZv)

// One wave (64 lanes) per ray. Lanes cooperatively walk the segments
// (coalesced tvals reads), predicated volume gathers, shuffle-reduce, lane 0
// writes B outputs.
//
// NUMERICS (hard-won, rounds 1-3): segment midpoints bounded by two adjacent
// x-plane crossings land EXACTLY on floor() discontinuities (planes at i-0.5
// -> midpoint at integer i in exact arithmetic). The harness golden ref is
// float32 numpy with SEPARATE mul-then-add rounding. hipcc's default
// -ffp-contract=fast fuses  a + tm*d  into FMA (single rounding) -> ~flips a
// large fraction of knife-edge floors -> absmax ~18.7 (threshold 1.25).
// ROCm's __fmul_rn/__fadd_rn are plain inline a*b / a+b and get contracted
// anyway (R2 was bit-identical to R1). f64 evaluation also mismatches (19.75,
// R3) because the ref's own f32 rounding noise decides the coin flips.
// FIX: pin the product tm*d in a VGPR via empty asm so the backend CANNOT
// fuse it into the following add; plus contract(off) pragma for the scope.
template <int BT>
__global__ __launch_bounds__(256) void ct_fwd(
    const float* __restrict__ vol,    // (B, NX, NY, NZ)
    const float* __restrict__ tvals,  // (R, S) sorted, +inf padded
    const float* __restrict__ Mm,     // (3,3)
    const float* __restrict__ bb,     // (3,)
    const float* __restrict__ src,    // (R,3)
    const float* __restrict__ dst,    // (R,3)
    float* __restrict__ out,          // (B, R)
    int R, int S, int B)
{
#pragma clang fp contract(off)
    const int lane = threadIdx.x & 63;
    const int wib  = threadIdx.x >> 6;
    const int r    = blockIdx.x * (blockDim.x >> 6) + wib;
    if (r >= R) return;

    // --- per-ray geometry (all lanes redundantly; broadcast loads) ---
    const float sx = src[r * 3 + 0], sy = src[r * 3 + 1], sz = src[r * 3 + 2];
    const float ex = dst[r * 3 + 0], ey = dst[r * 3 + 1], ez = dst[r * 3 + 2];
    const float M00 = Mm[0], M01 = Mm[1], M02 = Mm[2];
    const float M10 = Mm[3], M11 = Mm[4], M12 = Mm[5];
    const float M20 = Mm[6], M21 = Mm[7], M22 = Mm[8];
    const float b0 = bb[0], b1 = bb[1], b2 = bb[2];

    const float ax = M00 * sx + M01 * sy + M02 * sz + b0;
    const float ay = M10 * sx + M11 * sy + M12 * sz + b1;
    const float az = M20 * sx + M21 * sy + M22 * sz + b2;
    const float vx = ex - sx, vy = ey - sy, vz = ez - sz;
    const float dx = M00 * vx + M01 * vy + M02 * vz;
    const float dy = M10 * vx + M11 * vy + M12 * vz;
    const float dz = M20 * vx + M21 * vy + M22 * vz;
    const float raylen = sqrtf(vx * vx + vy * vy + vz * vz);

    const float INF = __builtin_inff();
    const long tbase = (long)r * S;

    float acc[BT];
#pragma unroll
    for (int c = 0; c < BT; ++c) acc[c] = 0.0f;

    const int nseg = S - 1;
    for (int s = lane; s < nseg; s += 64) {
        const float t0 = tvals[tbase + s];
        // sorted with +inf at the tail: if no active lane sees a finite t0,
        // nothing later can be valid.
        if (__ballot(t0 < INF) == 0ull) break;
        const float t1 = tvals[tbase + s + 1];
        if ((t0 < INF) && (t1 < INF) && (t1 > t0)) {
            // tmid = 0.5*(t0+t1); pts = a + tmid*d -- MUST be separate
            // f32 roundings (no FMA). The empty asm pins the product in a
            // VGPR so the backend cannot contract it into the add.
            const float tm = 0.5f * (t0 + t1);
            float mx = tm * dx; asm volatile("" : "+v"(mx));
            float my = tm * dy; asm volatile("" : "+v"(my));
            float mz = tm * dz; asm volatile("" : "+v"(mz));
            const float px = ax + mx;
            const float py = ay + my;
            const float pz = az + mz;
            const int ix = (int)floorf(px);
            const int iy = (int)floorf(py);
            const int iz = (int)floorf(pz);
            if ((unsigned)ix < NXv && (unsigned)iy < NYv && (unsigned)iz < NZv) {
                const float w = (t1 - t0) * raylen;
                const int flat = ((ix * NYv) + iy) * NZv + iz;
#pragma unroll
                for (int c = 0; c < BT; ++c) {
                    acc[c] += w * vol[(long)c * NVOX + flat];
                }
            }
        }
    }

    // --- wave reduction + write ---
#pragma unroll
    for (int c = 0; c < BT; ++c) {
        float v = acc[c];
#pragma unroll
        for (int off = 32; off > 0; off >>= 1) v += __shfl_xor(v, off, 64);
        if (lane == 0) out[(long)c * R + r] = v;
    }
}

extern "C" void kernel_launch(void* const* d_in, const int* in_sizes, int n_in,
                              void* d_out, int out_size, void* d_ws, size_t ws_size,
                              hipStream_t stream) {
    const float* vol   = (const float*)d_in[0];
    const float* tvals = (const float*)d_in[1];
    const float* Mm    = (const float*)d_in[2];
    const float* bb    = (const float*)d_in[3];
    const float* src   = (const float*)d_in[4];
    const float* dst   = (const float*)d_in[5];
    float* out = (float*)d_out;

    const int R = in_sizes[5] / 3;          // rays
    const int S = in_sizes[1] / R;          // t-values per ray
    const int B = in_sizes[0] / NVOX;       // batch of volumes

    const int wavesPerBlock = 4;            // block = 256 threads
    const int blocks = (R + wavesPerBlock - 1) / wavesPerBlock;
    dim3 grid(blocks), block(wavesPerBlock * 64);

    if (B == 2) {
        ct_fwd<2><<<grid, block, 0, stream>>>(vol, tvals, Mm, bb, src, dst, out, R, S, B);
    } else if (B == 1) {
        ct_fwd<1><<<grid, block, 0, stream>>>(vol, tvals, Mm, bb, src, dst, out, R, S, B);
    } else if (B == 4) {
        ct_fwd<4><<<grid, block, 0, stream>>>(vol, tvals, Mm, bb, src, dst, out, R, S, B);
    } else {
        int c = 0;
        for (; c + 2 <= B; c += 2)
            ct_fwd<2><<<grid, block, 0, stream>>>(vol + (long)c * NVOX, tvals, Mm, bb,
                                                  src, dst, out + (long)c * R, R, S, B);
        for (; c < B; ++c)
            ct_fwd<1><<<grid, block, 0, stream>>>(vol + (long)c * NVOX, tvals, Mm, bb,
                                                  src, dst, out + (long)c * R, R, S, B);
    }
}